// Round 2
// baseline (811.679 us; speedup 1.0000x reference)
//
#include <hip/hip_runtime.h>
#include <hip/hip_bf16.h>

#define N_NODES    100000
#define N_EDGES    1200000
#define NUM_GRAPHS 128
#define IN_DIM     5
#define HIDDEN     64

// ---------------- Layer 1 edge scatter: agg1[dst] += x[src]  (5 dims) -------
__global__ void scatter1(const float* __restrict__ x,
                         const int* __restrict__ src,
                         const int* __restrict__ dst,
                         float* __restrict__ agg1) {
    int e = blockIdx.x * blockDim.x + threadIdx.x;
    if (e >= N_EDGES) return;
    int s = src[e], t = dst[e];
#pragma unroll
    for (int k = 0; k < IN_DIM; ++k)
        atomicAdd(&agg1[t * IN_DIM + k], x[s * IN_DIM + k]);
}

// ---------------- Layer 1 node transform: h1 = relu(agg1@Wr + b + x@Wo) -----
__global__ void node_mlp1(const float* __restrict__ agg1,
                          const float* __restrict__ x,
                          const float* __restrict__ w_rel1,
                          const float* __restrict__ b_rel1,
                          const float* __restrict__ w_root1,
                          float* __restrict__ h1) {
    int gid = blockIdx.x * blockDim.x + threadIdx.x;
    if (gid >= N_NODES * HIDDEN) return;
    int node = gid >> 6, d = gid & 63;
    float acc = b_rel1[d];
#pragma unroll
    for (int k = 0; k < IN_DIM; ++k) {
        acc += agg1[node * IN_DIM + k] * w_rel1[k * HIDDEN + d];
        acc += x[node * IN_DIM + k]    * w_root1[k * HIDDEN + d];
    }
    h1[gid] = fmaxf(acc, 0.0f);
}

// ---------------- Layer 2 edge scatter: agg2[dst,:] += h1[src,:] (64 dims) --
// one thread per (edge, dim): a wave handles exactly one edge row (256B read)
__global__ void scatter2(const float* __restrict__ h1,
                         const int* __restrict__ src,
                         const int* __restrict__ dst,
                         float* __restrict__ agg2) {
    unsigned gid = blockIdx.x * blockDim.x + threadIdx.x;
    if (gid >= (unsigned)N_EDGES * HIDDEN) return;
    unsigned e = gid >> 6, d = gid & 63;
    int s = src[e], t = dst[e];
    atomicAdd(&agg2[(size_t)t * HIDDEN + d], h1[(size_t)s * HIDDEN + d]);
}

// ---- Layer 2 node transform fused with add-pool accumulation --------------
// h2 = relu(agg2@Wr + b + h1@Wo); add_pool[batch[node]] += h2  (never stored)
#define NPB 16
__global__ void node_mlp2_pool(const float* __restrict__ agg2,
                               const float* __restrict__ h1,
                               const float* __restrict__ w_rel2,
                               const float* __restrict__ b_rel2,
                               const float* __restrict__ w_root2,
                               const int* __restrict__ batch,
                               float* __restrict__ add_pool) {
    __shared__ float s_wrel[HIDDEN * HIDDEN];
    __shared__ float s_wroot[HIDDEN * HIDDEN];
    int t = threadIdx.x;
    for (int i = t; i < HIDDEN * HIDDEN; i += 256) {
        s_wrel[i]  = w_rel2[i];
        s_wroot[i] = w_root2[i];
    }
    __syncthreads();

    int d = t & 63, r = t >> 6;          // 4 rows of 64 lanes
    int base = blockIdx.x * NPB;
    float bias = b_rel2[d];
    for (int rr = r; rr < NPB; rr += 4) {
        int node = base + rr;
        if (node >= N_NODES) break;
        const float* arow = agg2 + (size_t)node * HIDDEN;
        const float* hrow = h1   + (size_t)node * HIDDEN;
        float acc = bias;
#pragma unroll 8
        for (int k = 0; k < HIDDEN; ++k) {
            acc += arow[k] * s_wrel[k * HIDDEN + d];
            acc += hrow[k] * s_wroot[k * HIDDEN + d];
        }
        float h2v = fmaxf(acc, 0.0f);
        atomicAdd(&add_pool[(size_t)batch[node] * HIDDEN + d], h2v);
    }
}

// ---------------- MLP head: out[g] from [mean_pool || add_pool] -------------
__device__ __forceinline__ int lower_bound_i(const int* a, int n, int v) {
    int lo = 0, hi = n;
    while (lo < hi) { int mid = (lo + hi) >> 1; if (a[mid] < v) lo = mid + 1; else hi = mid; }
    return lo;
}

__global__ void head_mlp(const float* __restrict__ add_pool,
                         const int* __restrict__ batch,
                         const float* __restrict__ w_h1,
                         const float* __restrict__ b_h1,
                         const float* __restrict__ w_h2,
                         const float* __restrict__ b_h2,
                         float* __restrict__ out) {
    int g = blockIdx.x;                  // one block (64 threads) per graph
    int t = threadIdx.x;

    __shared__ int s_cnt;
    if (t == 0) {
        int start = lower_bound_i(batch, N_NODES, g);
        int end   = lower_bound_i(batch, N_NODES, g + 1);
        s_cnt = end - start;
    }
    __syncthreads();
    float cnt = fmaxf((float)s_cnt, 1.0f);

    __shared__ float s_g[2 * HIDDEN];
    float add = add_pool[(size_t)g * HIDDEN + t];
    s_g[t]          = add / cnt;   // mean_pool
    s_g[HIDDEN + t] = add;         // add_pool
    __syncthreads();

    float hid = b_h1[t];
#pragma unroll 16
    for (int i = 0; i < 2 * HIDDEN; ++i)
        hid += s_g[i] * w_h1[i * HIDDEN + t];
    hid = fmaxf(hid, 0.0f);

    float res = hid * w_h2[t];
    for (int off = 32; off > 0; off >>= 1)
        res += __shfl_down(res, off, 64);
    if (t == 0)
        out[g] = res + b_h2[0];
}

extern "C" void kernel_launch(void* const* d_in, const int* in_sizes, int n_in,
                              void* d_out, int out_size, void* d_ws, size_t ws_size,
                              hipStream_t stream) {
    const float* x       = (const float*)d_in[0];
    const int*   ei      = (const int*)d_in[1];
    const int*   src     = ei;
    const int*   dst     = ei + N_EDGES;
    const int*   batch   = (const int*)d_in[2];
    const float* w_rel1  = (const float*)d_in[3];
    const float* b_rel1  = (const float*)d_in[4];
    const float* w_root1 = (const float*)d_in[5];
    const float* w_rel2  = (const float*)d_in[6];
    const float* b_rel2  = (const float*)d_in[7];
    const float* w_root2 = (const float*)d_in[8];
    const float* w_h1    = (const float*)d_in[9];
    const float* b_h1    = (const float*)d_in[10];
    const float* w_h2    = (const float*)d_in[11];
    const float* b_h2    = (const float*)d_in[12];
    float* out = (float*)d_out;

    // workspace layout (all fp32):
    // [agg1: N*5 | agg2: N*64 | add_pool: 128*64 | h1: N*64]
    float* agg1     = (float*)d_ws;
    float* agg2     = agg1 + (size_t)N_NODES * IN_DIM;
    float* add_pool = agg2 + (size_t)N_NODES * HIDDEN;
    float* h1       = add_pool + (size_t)NUM_GRAPHS * HIDDEN;

    // zero the atomic accumulators (contiguous prefix)
    size_t zero_bytes = sizeof(float) *
        ((size_t)N_NODES * (IN_DIM + HIDDEN) + (size_t)NUM_GRAPHS * HIDDEN);
    hipMemsetAsync(d_ws, 0, zero_bytes, stream);

    scatter1<<<(N_EDGES + 255) / 256, 256, 0, stream>>>(x, src, dst, agg1);
    node_mlp1<<<(N_NODES * HIDDEN + 255) / 256, 256, 0, stream>>>(
        agg1, x, w_rel1, b_rel1, w_root1, h1);
    scatter2<<<((unsigned)N_EDGES * HIDDEN + 255) / 256, 256, 0, stream>>>(
        h1, src, dst, agg2);
    node_mlp2_pool<<<(N_NODES + NPB - 1) / NPB, 256, 0, stream>>>(
        agg2, h1, w_rel2, b_rel2, w_root2, batch, add_pool);
    head_mlp<<<NUM_GRAPHS, 64, 0, stream>>>(
        add_pool, batch, w_h1, b_h1, w_h2, b_h2, out);
}

// Round 3
// 711.173 us; speedup vs baseline: 1.1413x; 1.1413x over previous
//
#include <hip/hip_runtime.h>
#include <hip/hip_bf16.h>

#define N_NODES    100000
#define N_EDGES    1200000
#define NUM_GRAPHS 128
#define IN_DIM     5
#define HIDDEN     64

#define SCAN_BLOCK 256
#define SCAN_CHUNK 4
#define SCAN_TILE  (SCAN_BLOCK * SCAN_CHUNK)                  // 1024
#define SCAN_NB    ((N_NODES + SCAN_TILE - 1) / SCAN_TILE)    // 98

__device__ __forceinline__ int rfl(int v) { return __builtin_amdgcn_readfirstlane(v); }

// ---- CSR build step 1: in-degree histogram (ptr[n] = deg(n)) ---------------
__global__ void hist_kernel(const int* __restrict__ dst, int* __restrict__ ptr) {
    int i = blockIdx.x * blockDim.x + threadIdx.x;      // 4 edges per thread
    if (i * 4 >= N_EDGES) return;
    int4 d = ((const int4*)dst)[i];
    atomicAdd(&ptr[d.x], 1);
    atomicAdd(&ptr[d.y], 1);
    atomicAdd(&ptr[d.z], 1);
    atomicAdd(&ptr[d.w], 1);
}

// ---- CSR build step 2a: per-block exclusive scan (in place) ----------------
__global__ void scan1_kernel(int* __restrict__ ptr, int* __restrict__ blockSums) {
    __shared__ int s[SCAN_BLOCK];
    int t = threadIdx.x, b = blockIdx.x;
    int base = b * SCAN_TILE + t * SCAN_CHUNK;
    int v[SCAN_CHUNK];
    int sum = 0;
#pragma unroll
    for (int i = 0; i < SCAN_CHUNK; ++i) {
        int idx = base + i;
        v[i] = (idx < N_NODES) ? ptr[idx] : 0;
        sum += v[i];
    }
    s[t] = sum;
    __syncthreads();
    for (int off = 1; off < SCAN_BLOCK; off <<= 1) {
        int x = (t >= off) ? s[t - off] : 0;
        __syncthreads();
        s[t] += x;
        __syncthreads();
    }
    if (t == SCAN_BLOCK - 1) blockSums[b] = s[t];
    int run = s[t] - sum;                 // exclusive offset within block
#pragma unroll
    for (int i = 0; i < SCAN_CHUNK; ++i) {
        int idx = base + i;
        if (idx < N_NODES) ptr[idx] = run;
        run += v[i];
    }
}

// ---- CSR build step 2b: scan the 98 block sums (single block) --------------
__global__ void scan2_kernel(int* __restrict__ blockSums) {
    __shared__ int s[128];
    int t = threadIdx.x;
    int v = (t < SCAN_NB) ? blockSums[t] : 0;
    s[t] = v;
    __syncthreads();
    for (int off = 1; off < 128; off <<= 1) {
        int x = (t >= off) ? s[t - off] : 0;
        __syncthreads();
        s[t] += x;
        __syncthreads();
    }
    if (t < SCAN_NB) blockSums[t] = s[t] - v;   // exclusive
}

// ---- CSR build step 2c: add block offsets ----------------------------------
__global__ void scan3_kernel(int* __restrict__ ptr, const int* __restrict__ blockSums) {
    int i = blockIdx.x * blockDim.x + threadIdx.x;
    if (i < N_NODES) ptr[i] += blockSums[i / SCAN_TILE];
}

// ---- CSR build step 3: fill sorted src list --------------------------------
// after this, ptr[n] == end(n); start(n) == (n ? ptr[n-1] : 0)
__global__ void fill_kernel(const int* __restrict__ src, const int* __restrict__ dst,
                            int* __restrict__ ptr, int* __restrict__ esrc) {
    int i = blockIdx.x * blockDim.x + threadIdx.x;      // 4 edges per thread
    if (i * 4 >= N_EDGES) return;
    int4 s = ((const int4*)src)[i];
    int4 d = ((const int4*)dst)[i];
    esrc[atomicAdd(&ptr[d.x], 1)] = s.x;
    esrc[atomicAdd(&ptr[d.y], 1)] = s.y;
    esrc[atomicAdd(&ptr[d.z], 1)] = s.z;
    esrc[atomicAdd(&ptr[d.w], 1)] = s.w;
}

// ---- Layer 1: gather agg1 (5 dims) + transform -> h1, one wave per node ----
__global__ void gather_mlp1(const float* __restrict__ x,
                            const int* __restrict__ ptr,
                            const int* __restrict__ esrc,
                            const float* __restrict__ w_rel1,
                            const float* __restrict__ b_rel1,
                            const float* __restrict__ w_root1,
                            float* __restrict__ h1) {
    int lane = threadIdx.x & 63;
    int w    = (blockIdx.x * blockDim.x + threadIdx.x) >> 6;
    int nw   = (gridDim.x * blockDim.x) >> 6;

    float wr[IN_DIM], wo[IN_DIM];
#pragma unroll
    for (int k = 0; k < IN_DIM; ++k) {
        wr[k] = w_rel1[k * HIDDEN + lane];
        wo[k] = w_root1[k * HIDDEN + lane];
    }
    float bias = b_rel1[lane];

    for (int n = w; n < N_NODES; n += nw) {
        int start = rfl(n ? ptr[n - 1] : 0);
        int end   = rfl(ptr[n]);
        float a[IN_DIM] = {0.f, 0.f, 0.f, 0.f, 0.f};
        for (int e = start + lane; e < end; e += 64) {
            int s = esrc[e];
#pragma unroll
            for (int k = 0; k < IN_DIM; ++k) a[k] += x[s * IN_DIM + k];
        }
#pragma unroll
        for (int k = 0; k < IN_DIM; ++k)
#pragma unroll
            for (int off = 1; off < 64; off <<= 1)
                a[k] += __shfl_xor(a[k], off, 64);
        float acc = bias;
#pragma unroll
        for (int k = 0; k < IN_DIM; ++k)
            acc += a[k] * wr[k] + x[n * IN_DIM + k] * wo[k];
        h1[(size_t)n * HIDDEN + lane] = fmaxf(acc, 0.0f);
    }
}

// ---- Layer 2 aggregate: agg2[n][d] = sum h1[esrc][d], one wave per node ----
__global__ void gather2_kernel(const float* __restrict__ h1,
                               const int* __restrict__ ptr,
                               const int* __restrict__ esrc,
                               float* __restrict__ agg2) {
    int lane = threadIdx.x & 63;
    int w    = (blockIdx.x * blockDim.x + threadIdx.x) >> 6;
    int nw   = (gridDim.x * blockDim.x) >> 6;
    for (int n = w; n < N_NODES; n += nw) {
        int start = rfl(n ? ptr[n - 1] : 0);
        int end   = rfl(ptr[n]);
        float a0 = 0.f, a1 = 0.f, a2 = 0.f, a3 = 0.f;
        int e = start;
        for (; e + 3 < end; e += 4) {
            int s0 = esrc[e], s1 = esrc[e + 1], s2 = esrc[e + 2], s3 = esrc[e + 3];
            a0 += h1[(size_t)s0 * HIDDEN + lane];
            a1 += h1[(size_t)s1 * HIDDEN + lane];
            a2 += h1[(size_t)s2 * HIDDEN + lane];
            a3 += h1[(size_t)s3 * HIDDEN + lane];
        }
        for (; e < end; ++e) a0 += h1[(size_t)esrc[e] * HIDDEN + lane];
        agg2[(size_t)n * HIDDEN + lane] = (a0 + a1) + (a2 + a3);
    }
}

// ---- Layer 2 transform: h2 = relu(agg2@Wr + b + h1@Wo), IN PLACE over agg2 -
// lane d keeps weight columns Wrel[:,d], Wroot[:,d] in 128 VGPRs; A-row
// elements arrive as wave-uniform broadcast float4 loads (no LDS pipe).
__global__ void mlp2_kernel(float* __restrict__ agg2,          // in: agg2, out: h2
                            const float* __restrict__ h1,
                            const float* __restrict__ w_rel2,
                            const float* __restrict__ b_rel2,
                            const float* __restrict__ w_root2) {
    int lane = threadIdx.x & 63;
    float wr[HIDDEN], wo[HIDDEN];
#pragma unroll
    for (int k = 0; k < HIDDEN; ++k) {
        wr[k] = w_rel2[k * HIDDEN + lane];
        wo[k] = w_root2[k * HIDDEN + lane];
    }
    float bias = b_rel2[lane];

    int w  = (blockIdx.x * blockDim.x + threadIdx.x) >> 6;
    int nw = (gridDim.x * blockDim.x) >> 6;
    for (int n = w; n < N_NODES; n += nw) {
        const float4* ar = (const float4*)(agg2 + (size_t)n * HIDDEN);
        const float4* hr = (const float4*)(h1   + (size_t)n * HIDDEN);
        float acc = bias;
#pragma unroll
        for (int q = 0; q < HIDDEN / 4; ++q) {
            float4 a = ar[q], h = hr[q];
            acc += a.x * wr[4 * q + 0] + a.y * wr[4 * q + 1]
                 + a.z * wr[4 * q + 2] + a.w * wr[4 * q + 3];
            acc += h.x * wo[4 * q + 0] + h.y * wo[4 * q + 1]
                 + h.z * wo[4 * q + 2] + h.w * wo[4 * q + 3];
        }
        agg2[(size_t)n * HIDDEN + lane] = fmaxf(acc, 0.0f);
    }
}

// ---- Pool (add+mean over sorted batch) + MLP head --------------------------
__device__ __forceinline__ int lower_bound_i(const int* a, int n, int v) {
    int lo = 0, hi = n;
    while (lo < hi) { int mid = (lo + hi) >> 1; if (a[mid] < v) lo = mid + 1; else hi = mid; }
    return lo;
}

__global__ void pool_head(const float* __restrict__ h2,
                          const int* __restrict__ batch,
                          const float* __restrict__ w_h1,
                          const float* __restrict__ b_h1,
                          const float* __restrict__ w_h2,
                          const float* __restrict__ b_h2,
                          float* __restrict__ out) {
    int g = blockIdx.x, t = threadIdx.x;
    int d = t & 63, r = t >> 6;

    __shared__ int s_range[2];
    if (t == 0) {
        s_range[0] = lower_bound_i(batch, N_NODES, g);
        s_range[1] = lower_bound_i(batch, N_NODES, g + 1);
    }
    __syncthreads();
    int start = s_range[0], end = s_range[1];

    float acc = 0.0f;
    for (int n = start + r; n < end; n += 4)
        acc += h2[(size_t)n * HIDDEN + d];

    __shared__ float sp[256];
    sp[t] = acc;
    __syncthreads();

    __shared__ float sg[2 * HIDDEN];
    if (r == 0) {
        float add = sp[d] + sp[64 + d] + sp[128 + d] + sp[192 + d];
        float cnt = fmaxf((float)(end - start), 1.0f);
        sg[d]          = add / cnt;   // mean_pool
        sg[HIDDEN + d] = add;         // add_pool
    }
    __syncthreads();

    if (t < 64) {
        float hid = b_h1[t];
#pragma unroll 16
        for (int i = 0; i < 2 * HIDDEN; ++i)
            hid += sg[i] * w_h1[i * HIDDEN + t];
        hid = fmaxf(hid, 0.0f);
        float res = hid * w_h2[t];
        for (int off = 32; off > 0; off >>= 1)
            res += __shfl_down(res, off, 64);
        if (t == 0) out[g] = res + b_h2[0];
    }
}

extern "C" void kernel_launch(void* const* d_in, const int* in_sizes, int n_in,
                              void* d_out, int out_size, void* d_ws, size_t ws_size,
                              hipStream_t stream) {
    const float* x       = (const float*)d_in[0];
    const int*   ei      = (const int*)d_in[1];
    const int*   src     = ei;
    const int*   dst     = ei + N_EDGES;
    const int*   batch   = (const int*)d_in[2];
    const float* w_rel1  = (const float*)d_in[3];
    const float* b_rel1  = (const float*)d_in[4];
    const float* w_root1 = (const float*)d_in[5];
    const float* w_rel2  = (const float*)d_in[6];
    const float* b_rel2  = (const float*)d_in[7];
    const float* w_root2 = (const float*)d_in[8];
    const float* w_h1    = (const float*)d_in[9];
    const float* b_h1    = (const float*)d_in[10];
    const float* w_h2    = (const float*)d_in[11];
    const float* b_h2    = (const float*)d_in[12];
    float* out = (float*)d_out;

    // workspace layout:
    // [ptr: N ints | blockSums: 128 ints | esrc: E ints | h1: N*64 f32 | agg2/h2: N*64 f32]
    int*   ptr       = (int*)d_ws;
    int*   blockSums = ptr + ((N_NODES + 31) & ~31);
    int*   esrc      = blockSums + 128;
    float* h1        = (float*)(esrc + N_EDGES);
    float* agg2      = h1 + (size_t)N_NODES * HIDDEN;

    hipMemsetAsync(ptr, 0, sizeof(int) * N_NODES, stream);

    hist_kernel<<<(N_EDGES / 4 + 255) / 256, 256, 0, stream>>>(dst, ptr);
    scan1_kernel<<<SCAN_NB, SCAN_BLOCK, 0, stream>>>(ptr, blockSums);
    scan2_kernel<<<1, 128, 0, stream>>>(blockSums);
    scan3_kernel<<<(N_NODES + 255) / 256, 256, 0, stream>>>(ptr, blockSums);
    fill_kernel<<<(N_EDGES / 4 + 255) / 256, 256, 0, stream>>>(src, dst, ptr, esrc);

    gather_mlp1<<<1024, 256, 0, stream>>>(x, ptr, esrc, w_rel1, b_rel1, w_root1, h1);
    gather2_kernel<<<2048, 256, 0, stream>>>(h1, ptr, esrc, agg2);
    mlp2_kernel<<<1024, 256, 0, stream>>>(agg2, h1, w_rel2, b_rel2, w_root2);
    pool_head<<<NUM_GRAPHS, 256, 0, stream>>>(agg2, batch, w_h1, b_h1, w_h2, b_h2, out);
}

// Round 4
// 373.299 us; speedup vs baseline: 2.1743x; 1.9051x over previous
//
#include <hip/hip_runtime.h>
#include <hip/hip_bf16.h>

#define N_NODES    100000
#define N_EDGES    1200000
#define NUM_GRAPHS 128
#define IN_DIM     5
#define HIDDEN     64
#define M_TILES    (N_NODES / 16)   // 6250 (exact)

#define SCAN_BLOCK 256
#define SCAN_CHUNK 4
#define SCAN_TILE  (SCAN_BLOCK * SCAN_CHUNK)                  // 1024
#define SCAN_NB    ((N_NODES + SCAN_TILE - 1) / SCAN_TILE)    // 98

typedef __attribute__((ext_vector_type(8))) short short8;   // 8 bf16 (4 VGPRs)
typedef __attribute__((ext_vector_type(4))) float f32x4;

__device__ __forceinline__ int rfl(int v) { return __builtin_amdgcn_readfirstlane(v); }

// fp32 -> bf16 bits (RNE)
__device__ __forceinline__ unsigned short f2bs(float f) {
    union { float f; unsigned u; } v; v.f = f;
    return (unsigned short)((v.u + 0x7FFFu + ((v.u >> 16) & 1u)) >> 16);
}
// bf16 bits -> fp32
__device__ __forceinline__ float bs2f(unsigned short s) {
    union { unsigned u; float f; } v; v.u = ((unsigned)s) << 16;
    return v.f;
}

// ---- CSR build step 1: in-degree histogram (ptr[n] = deg(n)) ---------------
__global__ void hist_kernel(const int* __restrict__ dst, int* __restrict__ ptr) {
    int i = blockIdx.x * blockDim.x + threadIdx.x;      // 4 edges per thread
    if (i * 4 >= N_EDGES) return;
    int4 d = ((const int4*)dst)[i];
    atomicAdd(&ptr[d.x], 1);
    atomicAdd(&ptr[d.y], 1);
    atomicAdd(&ptr[d.z], 1);
    atomicAdd(&ptr[d.w], 1);
}

// ---- CSR build step 2a: per-block exclusive scan (in place) ----------------
__global__ void scan1_kernel(int* __restrict__ ptr, int* __restrict__ blockSums) {
    __shared__ int s[SCAN_BLOCK];
    int t = threadIdx.x, b = blockIdx.x;
    int base = b * SCAN_TILE + t * SCAN_CHUNK;
    int v[SCAN_CHUNK];
    int sum = 0;
#pragma unroll
    for (int i = 0; i < SCAN_CHUNK; ++i) {
        int idx = base + i;
        v[i] = (idx < N_NODES) ? ptr[idx] : 0;
        sum += v[i];
    }
    s[t] = sum;
    __syncthreads();
    for (int off = 1; off < SCAN_BLOCK; off <<= 1) {
        int x = (t >= off) ? s[t - off] : 0;
        __syncthreads();
        s[t] += x;
        __syncthreads();
    }
    if (t == SCAN_BLOCK - 1) blockSums[b] = s[t];
    int run = s[t] - sum;                 // exclusive offset within block
#pragma unroll
    for (int i = 0; i < SCAN_CHUNK; ++i) {
        int idx = base + i;
        if (idx < N_NODES) ptr[idx] = run;
        run += v[i];
    }
}

// ---- CSR build step 2b: scan the 98 block sums (single block) --------------
__global__ void scan2_kernel(int* __restrict__ blockSums) {
    __shared__ int s[128];
    int t = threadIdx.x;
    int v = (t < SCAN_NB) ? blockSums[t] : 0;
    s[t] = v;
    __syncthreads();
    for (int off = 1; off < 128; off <<= 1) {
        int x = (t >= off) ? s[t - off] : 0;
        __syncthreads();
        s[t] += x;
        __syncthreads();
    }
    if (t < SCAN_NB) blockSums[t] = s[t] - v;   // exclusive
}

// ---- CSR build step 2c: add block offsets ----------------------------------
__global__ void scan3_kernel(int* __restrict__ ptr, const int* __restrict__ blockSums) {
    int i = blockIdx.x * blockDim.x + threadIdx.x;
    if (i < N_NODES) ptr[i] += blockSums[i / SCAN_TILE];
}

// ---- CSR build step 3: fill sorted src list --------------------------------
// after this, ptr[n] == end(n); start(n) == (n ? ptr[n-1] : 0)
__global__ void fill_kernel(const int* __restrict__ src, const int* __restrict__ dst,
                            int* __restrict__ ptr, int* __restrict__ esrc) {
    int i = blockIdx.x * blockDim.x + threadIdx.x;      // 4 edges per thread
    if (i * 4 >= N_EDGES) return;
    int4 s = ((const int4*)src)[i];
    int4 d = ((const int4*)dst)[i];
    esrc[atomicAdd(&ptr[d.x], 1)] = s.x;
    esrc[atomicAdd(&ptr[d.y], 1)] = s.y;
    esrc[atomicAdd(&ptr[d.z], 1)] = s.z;
    esrc[atomicAdd(&ptr[d.w], 1)] = s.w;
}

// ---- Layer 1: gather agg1 (5 dims) + transform -> h1 (bf16), wave per node -
__global__ void gather_mlp1(const float* __restrict__ x,
                            const int* __restrict__ ptr,
                            const int* __restrict__ esrc,
                            const float* __restrict__ w_rel1,
                            const float* __restrict__ b_rel1,
                            const float* __restrict__ w_root1,
                            unsigned short* __restrict__ h1) {
    int lane = threadIdx.x & 63;
    int w    = (blockIdx.x * blockDim.x + threadIdx.x) >> 6;
    int nw   = (gridDim.x * blockDim.x) >> 6;

    float wr[IN_DIM], wo[IN_DIM];
#pragma unroll
    for (int k = 0; k < IN_DIM; ++k) {
        wr[k] = w_rel1[k * HIDDEN + lane];
        wo[k] = w_root1[k * HIDDEN + lane];
    }
    float bias = b_rel1[lane];

    for (int n = w; n < N_NODES; n += nw) {
        int start = rfl(n ? ptr[n - 1] : 0);
        int end   = rfl(ptr[n]);
        float a[IN_DIM] = {0.f, 0.f, 0.f, 0.f, 0.f};
        for (int e = start + lane; e < end; e += 64) {
            int s = esrc[e];
#pragma unroll
            for (int k = 0; k < IN_DIM; ++k) a[k] += x[s * IN_DIM + k];
        }
#pragma unroll
        for (int k = 0; k < IN_DIM; ++k)
#pragma unroll
            for (int off = 1; off < 64; off <<= 1)
                a[k] += __shfl_xor(a[k], off, 64);
        float acc = bias;
#pragma unroll
        for (int k = 0; k < IN_DIM; ++k)
            acc += a[k] * wr[k] + x[n * IN_DIM + k] * wo[k];
        h1[(size_t)n * HIDDEN + lane] = f2bs(fmaxf(acc, 0.0f));
    }
}

// ---- Layer 2 aggregate: agg2[n][d] = sum h1[esrc][d] (bf16 in/out) ---------
__global__ void gather2_kernel(const unsigned short* __restrict__ h1,
                               const int* __restrict__ ptr,
                               const int* __restrict__ esrc,
                               unsigned short* __restrict__ agg2) {
    int lane = threadIdx.x & 63;
    int w    = (blockIdx.x * blockDim.x + threadIdx.x) >> 6;
    int nw   = (gridDim.x * blockDim.x) >> 6;
    for (int n = w; n < N_NODES; n += nw) {
        int start = rfl(n ? ptr[n - 1] : 0);
        int end   = rfl(ptr[n]);
        float a0 = 0.f, a1 = 0.f, a2 = 0.f, a3 = 0.f;
        int e = start;
        for (; e + 3 < end; e += 4) {
            int s0 = esrc[e], s1 = esrc[e + 1], s2 = esrc[e + 2], s3 = esrc[e + 3];
            a0 += bs2f(h1[(size_t)s0 * HIDDEN + lane]);
            a1 += bs2f(h1[(size_t)s1 * HIDDEN + lane]);
            a2 += bs2f(h1[(size_t)s2 * HIDDEN + lane]);
            a3 += bs2f(h1[(size_t)s3 * HIDDEN + lane]);
        }
        for (; e < end; ++e) a0 += bs2f(h1[(size_t)esrc[e] * HIDDEN + lane]);
        agg2[(size_t)n * HIDDEN + lane] = f2bs((a0 + a1) + (a2 + a3));
    }
}

// ---- Layer 2 transform via MFMA: h2 = relu([agg2|h1] @ [Wr;Wo] + b) --------
// block = 4 waves = 16x64 C-tile; wave w owns cols [16w,16w+16).
// A-frag: lane holds A[m=lane&15][k=quad*8+j] -> contiguous ushort8 loads.
// B-frag: lane holds B[k=quad*8+j][n=lane&15] (weights, fp32->bf16 once).
// C/D: col=lane&15, row=quad*4+reg.
__global__ void mlp2_mfma(const unsigned short* __restrict__ agg2,
                          const unsigned short* __restrict__ h1,
                          const float* __restrict__ w_rel2,
                          const float* __restrict__ b_rel2,
                          const float* __restrict__ w_root2,
                          unsigned short* __restrict__ h2) {
    int lane = threadIdx.x & 63;
    int wv   = threadIdx.x >> 6;        // 0..3 column group
    int row  = lane & 15;
    int quad = lane >> 4;
    int n    = wv * 16 + row;           // this lane's output column

    short8 bwr[2], bwo[2];
#pragma unroll
    for (int s = 0; s < 2; ++s)
#pragma unroll
        for (int j = 0; j < 8; ++j) {
            int k = 32 * s + quad * 8 + j;
            bwr[s][j] = (short)f2bs(w_rel2[k * HIDDEN + n]);
            bwo[s][j] = (short)f2bs(w_root2[k * HIDDEN + n]);
        }
    float bias = b_rel2[n];

    for (int t = blockIdx.x; t < M_TILES; t += gridDim.x) {
        int m0 = t * 16;
        size_t rbase = (size_t)(m0 + row) * HIDDEN;
        short8 aa0 = *(const short8*)(agg2 + rbase + quad * 8);
        short8 aa1 = *(const short8*)(agg2 + rbase + 32 + quad * 8);
        short8 ah0 = *(const short8*)(h1   + rbase + quad * 8);
        short8 ah1 = *(const short8*)(h1   + rbase + 32 + quad * 8);

        f32x4 acc = {bias, bias, bias, bias};
        acc = __builtin_amdgcn_mfma_f32_16x16x32_bf16(aa0, bwr[0], acc, 0, 0, 0);
        acc = __builtin_amdgcn_mfma_f32_16x16x32_bf16(aa1, bwr[1], acc, 0, 0, 0);
        acc = __builtin_amdgcn_mfma_f32_16x16x32_bf16(ah0, bwo[0], acc, 0, 0, 0);
        acc = __builtin_amdgcn_mfma_f32_16x16x32_bf16(ah1, bwo[1], acc, 0, 0, 0);

#pragma unroll
        for (int i = 0; i < 4; ++i) {
            int m = m0 + quad * 4 + i;
            h2[(size_t)m * HIDDEN + n] = f2bs(fmaxf(acc[i], 0.0f));
        }
    }
}

// ---- Pool (add+mean over sorted batch) + MLP head --------------------------
__device__ __forceinline__ int lower_bound_i(const int* a, int n, int v) {
    int lo = 0, hi = n;
    while (lo < hi) { int mid = (lo + hi) >> 1; if (a[mid] < v) lo = mid + 1; else hi = mid; }
    return lo;
}

__global__ void pool_head(const unsigned short* __restrict__ h2,
                          const int* __restrict__ batch,
                          const float* __restrict__ w_h1,
                          const float* __restrict__ b_h1,
                          const float* __restrict__ w_h2,
                          const float* __restrict__ b_h2,
                          float* __restrict__ out) {
    int g = blockIdx.x, t = threadIdx.x;
    int d = t & 63, r = t >> 6;

    __shared__ int s_range[2];
    if (t == 0) {
        s_range[0] = lower_bound_i(batch, N_NODES, g);
        s_range[1] = lower_bound_i(batch, N_NODES, g + 1);
    }
    __syncthreads();
    int start = s_range[0], end = s_range[1];

    float acc = 0.0f;
    for (int n = start + r; n < end; n += 4)
        acc += bs2f(h2[(size_t)n * HIDDEN + d]);

    __shared__ float sp[256];
    sp[t] = acc;
    __syncthreads();

    __shared__ float sg[2 * HIDDEN];
    if (r == 0) {
        float add = sp[d] + sp[64 + d] + sp[128 + d] + sp[192 + d];
        float cnt = fmaxf((float)(end - start), 1.0f);
        sg[d]          = add / cnt;   // mean_pool
        sg[HIDDEN + d] = add;         // add_pool
    }
    __syncthreads();

    if (t < 64) {
        float hid = b_h1[t];
#pragma unroll 16
        for (int i = 0; i < 2 * HIDDEN; ++i)
            hid += sg[i] * w_h1[i * HIDDEN + t];
        hid = fmaxf(hid, 0.0f);
        float res = hid * w_h2[t];
        for (int off = 32; off > 0; off >>= 1)
            res += __shfl_down(res, off, 64);
        if (t == 0) out[g] = res + b_h2[0];
    }
}

extern "C" void kernel_launch(void* const* d_in, const int* in_sizes, int n_in,
                              void* d_out, int out_size, void* d_ws, size_t ws_size,
                              hipStream_t stream) {
    const float* x       = (const float*)d_in[0];
    const int*   ei      = (const int*)d_in[1];
    const int*   src     = ei;
    const int*   dst     = ei + N_EDGES;
    const int*   batch   = (const int*)d_in[2];
    const float* w_rel1  = (const float*)d_in[3];
    const float* b_rel1  = (const float*)d_in[4];
    const float* w_root1 = (const float*)d_in[5];
    const float* w_rel2  = (const float*)d_in[6];
    const float* b_rel2  = (const float*)d_in[7];
    const float* w_root2 = (const float*)d_in[8];
    const float* w_h1    = (const float*)d_in[9];
    const float* b_h1    = (const float*)d_in[10];
    const float* w_h2    = (const float*)d_in[11];
    const float* b_h2    = (const float*)d_in[12];
    float* out = (float*)d_out;

    // workspace layout:
    // [ptr: N ints | blockSums: 128 | esrc: E ints | h1: N*64 bf16 | agg2: N*64 bf16 | h2: N*64 bf16]
    int*            ptr       = (int*)d_ws;
    int*            blockSums = ptr + ((N_NODES + 31) & ~31);
    int*            esrc      = blockSums + 128;
    unsigned short* h1        = (unsigned short*)(esrc + N_EDGES);
    unsigned short* agg2      = h1 + (size_t)N_NODES * HIDDEN;
    unsigned short* h2        = agg2 + (size_t)N_NODES * HIDDEN;

    hipMemsetAsync(ptr, 0, sizeof(int) * N_NODES, stream);

    hist_kernel<<<(N_EDGES / 4 + 255) / 256, 256, 0, stream>>>(dst, ptr);
    scan1_kernel<<<SCAN_NB, SCAN_BLOCK, 0, stream>>>(ptr, blockSums);
    scan2_kernel<<<1, 128, 0, stream>>>(blockSums);
    scan3_kernel<<<(N_NODES + 255) / 256, 256, 0, stream>>>(ptr, blockSums);
    fill_kernel<<<(N_EDGES / 4 + 255) / 256, 256, 0, stream>>>(src, dst, ptr, esrc);

    gather_mlp1<<<1024, 256, 0, stream>>>(x, ptr, esrc, w_rel1, b_rel1, w_root1, h1);
    gather2_kernel<<<2048, 256, 0, stream>>>(h1, ptr, esrc, agg2);
    mlp2_mfma<<<2048, 256, 0, stream>>>(agg2, h1, w_rel2, b_rel2, w_root2, h2);
    pool_head<<<NUM_GRAPHS, 256, 0, stream>>>(h2, batch, w_h1, b_h1, w_h2, b_h2, out);
}

// Round 5
// 326.454 us; speedup vs baseline: 2.4863x; 1.1435x over previous
//
#include <hip/hip_runtime.h>
#include <hip/hip_bf16.h>

#define N_NODES    100000
#define N_EDGES    1200000
#define NUM_GRAPHS 128
#define IN_DIM     5
#define HIDDEN     64
#define M_TILES    (N_NODES / 16)   // 6250 (exact)

#define SCAN_BLOCK 256
#define SCAN_CHUNK 4
#define SCAN_TILE  (SCAN_BLOCK * SCAN_CHUNK)                  // 1024
#define SCAN_NB    ((N_NODES + SCAN_TILE - 1) / SCAN_TILE)    // 98

typedef __attribute__((ext_vector_type(8))) short short8;   // 8 bf16 (4 VGPRs)
typedef __attribute__((ext_vector_type(4))) float f32x4;

__device__ __forceinline__ int rfl(int v) { return __builtin_amdgcn_readfirstlane(v); }

// fp32 -> bf16 bits (RNE)
__device__ __forceinline__ unsigned short f2bs(float f) {
    union { float f; unsigned u; } v; v.f = f;
    return (unsigned short)((v.u + 0x7FFFu + ((v.u >> 16) & 1u)) >> 16);
}
// bf16 bits -> fp32
__device__ __forceinline__ float bs2f(unsigned short s) {
    union { unsigned u; float f; } v; v.u = ((unsigned)s) << 16;
    return v.f;
}

// ---- CSR step 1: count + per-edge rank (rank written coalesced) ------------
__global__ void hist_rank(const int* __restrict__ dst,
                          int* __restrict__ cnt,
                          int* __restrict__ rank) {
    int i = blockIdx.x * blockDim.x + threadIdx.x;      // 4 edges per thread
    if (i * 4 >= N_EDGES) return;
    int4 d = ((const int4*)dst)[i];
    int4 r;
    r.x = atomicAdd(&cnt[d.x], 1);
    r.y = atomicAdd(&cnt[d.y], 1);
    r.z = atomicAdd(&cnt[d.z], 1);
    r.w = atomicAdd(&cnt[d.w], 1);
    ((int4*)rank)[i] = r;
}

// ---- CSR step 2a: per-block exclusive scan (in place) ----------------------
__global__ void scan1_kernel(int* __restrict__ ptr, int* __restrict__ blockSums) {
    __shared__ int s[SCAN_BLOCK];
    int t = threadIdx.x, b = blockIdx.x;
    int base = b * SCAN_TILE + t * SCAN_CHUNK;
    int v[SCAN_CHUNK];
    int sum = 0;
#pragma unroll
    for (int i = 0; i < SCAN_CHUNK; ++i) {
        int idx = base + i;
        v[i] = (idx < N_NODES) ? ptr[idx] : 0;
        sum += v[i];
    }
    s[t] = sum;
    __syncthreads();
    for (int off = 1; off < SCAN_BLOCK; off <<= 1) {
        int x = (t >= off) ? s[t - off] : 0;
        __syncthreads();
        s[t] += x;
        __syncthreads();
    }
    if (t == SCAN_BLOCK - 1) blockSums[b] = s[t];
    int run = s[t] - sum;                 // exclusive offset within block
#pragma unroll
    for (int i = 0; i < SCAN_CHUNK; ++i) {
        int idx = base + i;
        if (idx < N_NODES) ptr[idx] = run;
        run += v[i];
    }
}

// ---- CSR step 2b: scan the 98 block sums (single block) --------------------
__global__ void scan2_kernel(int* __restrict__ blockSums) {
    __shared__ int s[128];
    int t = threadIdx.x;
    int v = (t < SCAN_NB) ? blockSums[t] : 0;
    s[t] = v;
    __syncthreads();
    for (int off = 1; off < 128; off <<= 1) {
        int x = (t >= off) ? s[t - off] : 0;
        __syncthreads();
        s[t] += x;
        __syncthreads();
    }
    if (t < SCAN_NB) blockSums[t] = s[t] - v;   // exclusive
}

// ---- CSR step 2c: add block offsets (ptr becomes final start offsets) ------
__global__ void scan3_kernel(int* __restrict__ ptr, const int* __restrict__ blockSums) {
    int i = blockIdx.x * blockDim.x + threadIdx.x;
    if (i < N_NODES) ptr[i] += blockSums[i / SCAN_TILE];
}

// ---- CSR step 3: fill sorted src list -- NO atomics ------------------------
__global__ void scatter_fill(const int* __restrict__ src, const int* __restrict__ dst,
                             const int* __restrict__ rank, const int* __restrict__ ptr,
                             int* __restrict__ esrc) {
    int i = blockIdx.x * blockDim.x + threadIdx.x;      // 4 edges per thread
    if (i * 4 >= N_EDGES) return;
    int4 s = ((const int4*)src)[i];
    int4 d = ((const int4*)dst)[i];
    int4 r = ((const int4*)rank)[i];
    esrc[ptr[d.x] + r.x] = s.x;
    esrc[ptr[d.y] + r.y] = s.y;
    esrc[ptr[d.z] + r.z] = s.z;
    esrc[ptr[d.w] + r.w] = s.w;
}

// ---- Layer 1: gather agg1 (5 dims) + transform -> h1 (bf16), wave per node -
__global__ void gather_mlp1(const float* __restrict__ x,
                            const int* __restrict__ ptr,
                            const int* __restrict__ esrc,
                            const float* __restrict__ w_rel1,
                            const float* __restrict__ b_rel1,
                            const float* __restrict__ w_root1,
                            unsigned short* __restrict__ h1) {
    int lane = threadIdx.x & 63;
    int w    = (blockIdx.x * blockDim.x + threadIdx.x) >> 6;
    int nw   = (gridDim.x * blockDim.x) >> 6;

    float wr[IN_DIM], wo[IN_DIM];
#pragma unroll
    for (int k = 0; k < IN_DIM; ++k) {
        wr[k] = w_rel1[k * HIDDEN + lane];
        wo[k] = w_root1[k * HIDDEN + lane];
    }
    float bias = b_rel1[lane];

    for (int n = w; n < N_NODES; n += nw) {
        int start = rfl(ptr[n]);
        int end   = rfl((n + 1 < N_NODES) ? ptr[n + 1] : N_EDGES);
        float a[IN_DIM] = {0.f, 0.f, 0.f, 0.f, 0.f};
        for (int e = start + lane; e < end; e += 64) {
            int s = esrc[e];
#pragma unroll
            for (int k = 0; k < IN_DIM; ++k) a[k] += x[s * IN_DIM + k];
        }
#pragma unroll
        for (int k = 0; k < IN_DIM; ++k)
#pragma unroll
            for (int off = 1; off < 64; off <<= 1)
                a[k] += __shfl_xor(a[k], off, 64);
        float acc = bias;
#pragma unroll
        for (int k = 0; k < IN_DIM; ++k)
            acc += a[k] * wr[k] + x[n * IN_DIM + k] * wo[k];
        h1[(size_t)n * HIDDEN + lane] = f2bs(fmaxf(acc, 0.0f));
    }
}

// ---- Layer 2 aggregate: agg2[n][:] = sum h1[esrc][:] -----------------------
// h1/agg2 viewed as dwords (2 bf16). Half-wave per edge: lane sub owns dims
// {2sub, 2sub+1}; halves interleave over the edge list, combined by shfl(32).
__global__ void gather2_kernel(const unsigned* __restrict__ h1,
                               const int* __restrict__ ptr,
                               const int* __restrict__ esrc,
                               unsigned* __restrict__ agg2) {
    int lane = threadIdx.x & 63;
    int sub  = lane & 31;
    int half = lane >> 5;
    int w    = (blockIdx.x * blockDim.x + threadIdx.x) >> 6;
    int nw   = (gridDim.x * blockDim.x) >> 6;
    for (int n = w; n < N_NODES; n += nw) {
        int start = rfl(ptr[n]);
        int end   = rfl((n + 1 < N_NODES) ? ptr[n + 1] : N_EDGES);
        float ax0 = 0.f, ay0 = 0.f, ax1 = 0.f, ay1 = 0.f;
        int e = start + half;
        for (; e + 2 < end; e += 4) {              // two edges per half-wave iter
            int s0 = esrc[e], s1 = esrc[e + 2];
            unsigned p0 = h1[(size_t)s0 * 32 + sub];
            unsigned p1 = h1[(size_t)s1 * 32 + sub];
            ax0 += bs2f((unsigned short)(p0 & 0xffff));
            ay0 += bs2f((unsigned short)(p0 >> 16));
            ax1 += bs2f((unsigned short)(p1 & 0xffff));
            ay1 += bs2f((unsigned short)(p1 >> 16));
        }
        if (e < end) {
            unsigned p = h1[(size_t)esrc[e] * 32 + sub];
            ax0 += bs2f((unsigned short)(p & 0xffff));
            ay0 += bs2f((unsigned short)(p >> 16));
        }
        float ax = ax0 + ax1, ay = ay0 + ay1;
        ax += __shfl_xor(ax, 32, 64);
        ay += __shfl_xor(ay, 32, 64);
        if (half == 0) {
            unsigned outw = ((unsigned)f2bs(ay) << 16) | (unsigned)f2bs(ax);
            agg2[(size_t)n * 32 + sub] = outw;
        }
    }
}

// ---- Layer 2 transform via MFMA: h2 = relu([agg2|h1] @ [Wr;Wo] + b) --------
__global__ void mlp2_mfma(const unsigned short* __restrict__ agg2,
                          const unsigned short* __restrict__ h1,
                          const float* __restrict__ w_rel2,
                          const float* __restrict__ b_rel2,
                          const float* __restrict__ w_root2,
                          unsigned short* __restrict__ h2) {
    int lane = threadIdx.x & 63;
    int wv   = threadIdx.x >> 6;        // 0..3 column group
    int row  = lane & 15;
    int quad = lane >> 4;
    int n    = wv * 16 + row;           // this lane's output column

    short8 bwr[2], bwo[2];
#pragma unroll
    for (int s = 0; s < 2; ++s)
#pragma unroll
        for (int j = 0; j < 8; ++j) {
            int k = 32 * s + quad * 8 + j;
            bwr[s][j] = (short)f2bs(w_rel2[k * HIDDEN + n]);
            bwo[s][j] = (short)f2bs(w_root2[k * HIDDEN + n]);
        }
    float bias = b_rel2[n];

    for (int t = blockIdx.x; t < M_TILES; t += gridDim.x) {
        int m0 = t * 16;
        size_t rbase = (size_t)(m0 + row) * HIDDEN;
        short8 aa0 = *(const short8*)(agg2 + rbase + quad * 8);
        short8 aa1 = *(const short8*)(agg2 + rbase + 32 + quad * 8);
        short8 ah0 = *(const short8*)(h1   + rbase + quad * 8);
        short8 ah1 = *(const short8*)(h1   + rbase + 32 + quad * 8);

        f32x4 acc = {bias, bias, bias, bias};
        acc = __builtin_amdgcn_mfma_f32_16x16x32_bf16(aa0, bwr[0], acc, 0, 0, 0);
        acc = __builtin_amdgcn_mfma_f32_16x16x32_bf16(aa1, bwr[1], acc, 0, 0, 0);
        acc = __builtin_amdgcn_mfma_f32_16x16x32_bf16(ah0, bwo[0], acc, 0, 0, 0);
        acc = __builtin_amdgcn_mfma_f32_16x16x32_bf16(ah1, bwo[1], acc, 0, 0, 0);

#pragma unroll
        for (int i = 0; i < 4; ++i) {
            int m = m0 + quad * 4 + i;
            h2[(size_t)m * HIDDEN + n] = f2bs(fmaxf(acc[i], 0.0f));
        }
    }
}

// ---- Pool (add+mean over sorted batch) + MLP head --------------------------
__device__ __forceinline__ int lower_bound_i(const int* a, int n, int v) {
    int lo = 0, hi = n;
    while (lo < hi) { int mid = (lo + hi) >> 1; if (a[mid] < v) lo = mid + 1; else hi = mid; }
    return lo;
}

__global__ void pool_head(const unsigned short* __restrict__ h2,
                          const int* __restrict__ batch,
                          const float* __restrict__ w_h1,
                          const float* __restrict__ b_h1,
                          const float* __restrict__ w_h2,
                          const float* __restrict__ b_h2,
                          float* __restrict__ out) {
    int g = blockIdx.x, t = threadIdx.x;
    int d = t & 63, r = t >> 6;

    __shared__ int s_range[2];
    if (t == 0) {
        s_range[0] = lower_bound_i(batch, N_NODES, g);
        s_range[1] = lower_bound_i(batch, N_NODES, g + 1);
    }
    __syncthreads();
    int start = s_range[0], end = s_range[1];

    float acc = 0.0f;
    for (int n = start + r; n < end; n += 4)
        acc += bs2f(h2[(size_t)n * HIDDEN + d]);

    __shared__ float sp[256];
    sp[t] = acc;
    __syncthreads();

    __shared__ float sg[2 * HIDDEN];
    if (r == 0) {
        float add = sp[d] + sp[64 + d] + sp[128 + d] + sp[192 + d];
        float cnt = fmaxf((float)(end - start), 1.0f);
        sg[d]          = add / cnt;   // mean_pool
        sg[HIDDEN + d] = add;         // add_pool
    }
    __syncthreads();

    if (t < 64) {
        float hid = b_h1[t];
#pragma unroll 16
        for (int i = 0; i < 2 * HIDDEN; ++i)
            hid += sg[i] * w_h1[i * HIDDEN + t];
        hid = fmaxf(hid, 0.0f);
        float res = hid * w_h2[t];
        for (int off = 32; off > 0; off >>= 1)
            res += __shfl_down(res, off, 64);
        if (t == 0) out[g] = res + b_h2[0];
    }
}

extern "C" void kernel_launch(void* const* d_in, const int* in_sizes, int n_in,
                              void* d_out, int out_size, void* d_ws, size_t ws_size,
                              hipStream_t stream) {
    const float* x       = (const float*)d_in[0];
    const int*   ei      = (const int*)d_in[1];
    const int*   src     = ei;
    const int*   dst     = ei + N_EDGES;
    const int*   batch   = (const int*)d_in[2];
    const float* w_rel1  = (const float*)d_in[3];
    const float* b_rel1  = (const float*)d_in[4];
    const float* w_root1 = (const float*)d_in[5];
    const float* w_rel2  = (const float*)d_in[6];
    const float* b_rel2  = (const float*)d_in[7];
    const float* w_root2 = (const float*)d_in[8];
    const float* w_h1    = (const float*)d_in[9];
    const float* b_h1    = (const float*)d_in[10];
    const float* w_h2    = (const float*)d_in[11];
    const float* b_h2    = (const float*)d_in[12];
    float* out = (float*)d_out;

    // workspace layout:
    // [ptr: N | blockSums: 128 | rank: E | esrc: E | h1: N*64 bf16 | agg2 | h2]
    int*            ptr       = (int*)d_ws;
    int*            blockSums = ptr + ((N_NODES + 31) & ~31);
    int*            rank      = blockSums + 128;
    int*            esrc      = rank + N_EDGES;
    unsigned short* h1        = (unsigned short*)(esrc + N_EDGES);
    unsigned short* agg2      = h1 + (size_t)N_NODES * HIDDEN;
    unsigned short* h2        = agg2 + (size_t)N_NODES * HIDDEN;

    hipMemsetAsync(ptr, 0, sizeof(int) * N_NODES, stream);

    hist_rank<<<(N_EDGES / 4 + 255) / 256, 256, 0, stream>>>(dst, ptr, rank);
    scan1_kernel<<<SCAN_NB, SCAN_BLOCK, 0, stream>>>(ptr, blockSums);
    scan2_kernel<<<1, 128, 0, stream>>>(blockSums);
    scan3_kernel<<<(N_NODES + 255) / 256, 256, 0, stream>>>(ptr, blockSums);
    scatter_fill<<<(N_EDGES / 4 + 255) / 256, 256, 0, stream>>>(src, dst, rank, ptr, esrc);

    gather_mlp1<<<1024, 256, 0, stream>>>(x, ptr, esrc, w_rel1, b_rel1, w_root1, h1);
    gather2_kernel<<<2048, 256, 0, stream>>>((const unsigned*)h1, ptr, esrc, (unsigned*)agg2);
    mlp2_mfma<<<2048, 256, 0, stream>>>(agg2, h1, w_rel2, b_rel2, w_root2, h2);
    pool_head<<<NUM_GRAPHS, 256, 0, stream>>>(h2, batch, w_h1, b_h1, w_h2, b_h2, out);
}

// Round 6
// 314.785 us; speedup vs baseline: 2.5785x; 1.0371x over previous
//
#include <hip/hip_runtime.h>
#include <hip/hip_bf16.h>

#define N_NODES    100000
#define N_EDGES    1200000
#define NUM_GRAPHS 128
#define IN_DIM     5
#define HIDDEN     64
#define M_TILES    (N_NODES / 16)   // 6250 (exact)

#define SCAN_BLOCK 256
#define SCAN_CHUNK 4
#define SCAN_TILE  (SCAN_BLOCK * SCAN_CHUNK)                  // 1024
#define SCAN_NB    ((N_NODES + SCAN_TILE - 1) / SCAN_TILE)    // 98

#define POOL_BLOCKS 256      // 1024 waves -> ~98 nodes per wave

typedef __attribute__((ext_vector_type(8))) short short8;   // 8 bf16 (4 VGPRs)
typedef __attribute__((ext_vector_type(4))) float f32x4;

__device__ __forceinline__ int rfl(int v) { return __builtin_amdgcn_readfirstlane(v); }

// fp32 -> bf16 bits (RNE)
__device__ __forceinline__ unsigned short f2bs(float f) {
    union { float f; unsigned u; } v; v.f = f;
    return (unsigned short)((v.u + 0x7FFFu + ((v.u >> 16) & 1u)) >> 16);
}
// bf16 bits -> fp32
__device__ __forceinline__ float bs2f(unsigned short s) {
    union { unsigned u; float f; } v; v.u = ((unsigned)s) << 16;
    return v.f;
}

// ---- CSR step 1: count + per-edge rank (rank written coalesced) ------------
__global__ void hist_rank(const int* __restrict__ dst,
                          int* __restrict__ cnt,
                          int* __restrict__ rank) {
    int i = blockIdx.x * blockDim.x + threadIdx.x;      // 4 edges per thread
    if (i * 4 >= N_EDGES) return;
    int4 d = ((const int4*)dst)[i];
    int4 r;
    r.x = atomicAdd(&cnt[d.x], 1);
    r.y = atomicAdd(&cnt[d.y], 1);
    r.z = atomicAdd(&cnt[d.z], 1);
    r.w = atomicAdd(&cnt[d.w], 1);
    ((int4*)rank)[i] = r;
}

// ---- CSR step 2a: per-block exclusive scan (in place) ----------------------
__global__ void scan1_kernel(int* __restrict__ ptr, int* __restrict__ blockSums) {
    __shared__ int s[SCAN_BLOCK];
    int t = threadIdx.x, b = blockIdx.x;
    int base = b * SCAN_TILE + t * SCAN_CHUNK;
    int v[SCAN_CHUNK];
    int sum = 0;
#pragma unroll
    for (int i = 0; i < SCAN_CHUNK; ++i) {
        int idx = base + i;
        v[i] = (idx < N_NODES) ? ptr[idx] : 0;
        sum += v[i];
    }
    s[t] = sum;
    __syncthreads();
    for (int off = 1; off < SCAN_BLOCK; off <<= 1) {
        int x = (t >= off) ? s[t - off] : 0;
        __syncthreads();
        s[t] += x;
        __syncthreads();
    }
    if (t == SCAN_BLOCK - 1) blockSums[b] = s[t];
    int run = s[t] - sum;                 // exclusive offset within block
#pragma unroll
    for (int i = 0; i < SCAN_CHUNK; ++i) {
        int idx = base + i;
        if (idx < N_NODES) ptr[idx] = run;
        run += v[i];
    }
}

// ---- CSR step 2b: scan the 98 block sums (single block) --------------------
__global__ void scan2_kernel(int* __restrict__ blockSums) {
    __shared__ int s[128];
    int t = threadIdx.x;
    int v = (t < SCAN_NB) ? blockSums[t] : 0;
    s[t] = v;
    __syncthreads();
    for (int off = 1; off < 128; off <<= 1) {
        int x = (t >= off) ? s[t - off] : 0;
        __syncthreads();
        s[t] += x;
        __syncthreads();
    }
    if (t < SCAN_NB) blockSums[t] = s[t] - v;   // exclusive
}

// ---- CSR step 2c: add block offsets (ptr becomes final start offsets) ------
__global__ void scan3_kernel(int* __restrict__ ptr, const int* __restrict__ blockSums) {
    int i = blockIdx.x * blockDim.x + threadIdx.x;
    if (i < N_NODES) ptr[i] += blockSums[i / SCAN_TILE];
}

// ---- CSR step 3: fill sorted src list -- NO atomics ------------------------
__global__ void scatter_fill(const int* __restrict__ src, const int* __restrict__ dst,
                             const int* __restrict__ rank, const int* __restrict__ ptr,
                             int* __restrict__ esrc) {
    int i = blockIdx.x * blockDim.x + threadIdx.x;      // 4 edges per thread
    if (i * 4 >= N_EDGES) return;
    int4 s = ((const int4*)src)[i];
    int4 d = ((const int4*)dst)[i];
    int4 r = ((const int4*)rank)[i];
    esrc[ptr[d.x] + r.x] = s.x;
    esrc[ptr[d.y] + r.y] = s.y;
    esrc[ptr[d.z] + r.z] = s.z;
    esrc[ptr[d.w] + r.w] = s.w;
}

// ---- Layer 1: gather agg1 (5 dims) + transform -> h1 (bf16), wave per node -
__global__ void gather_mlp1(const float* __restrict__ x,
                            const int* __restrict__ ptr,
                            const int* __restrict__ esrc,
                            const float* __restrict__ w_rel1,
                            const float* __restrict__ b_rel1,
                            const float* __restrict__ w_root1,
                            unsigned short* __restrict__ h1) {
    int lane = threadIdx.x & 63;
    int w    = (blockIdx.x * blockDim.x + threadIdx.x) >> 6;
    int nw   = (gridDim.x * blockDim.x) >> 6;

    float wr[IN_DIM], wo[IN_DIM];
#pragma unroll
    for (int k = 0; k < IN_DIM; ++k) {
        wr[k] = w_rel1[k * HIDDEN + lane];
        wo[k] = w_root1[k * HIDDEN + lane];
    }
    float bias = b_rel1[lane];

    for (int n = w; n < N_NODES; n += nw) {
        int start = rfl(ptr[n]);
        int end   = rfl((n + 1 < N_NODES) ? ptr[n + 1] : N_EDGES);
        float a[IN_DIM] = {0.f, 0.f, 0.f, 0.f, 0.f};
        for (int e = start + lane; e < end; e += 64) {
            int s = esrc[e];
#pragma unroll
            for (int k = 0; k < IN_DIM; ++k) a[k] += x[s * IN_DIM + k];
        }
#pragma unroll
        for (int k = 0; k < IN_DIM; ++k)
#pragma unroll
            for (int off = 1; off < 64; off <<= 1)
                a[k] += __shfl_xor(a[k], off, 64);
        float acc = bias;
#pragma unroll
        for (int k = 0; k < IN_DIM; ++k)
            acc += a[k] * wr[k] + x[n * IN_DIM + k] * wo[k];
        h1[(size_t)n * HIDDEN + lane] = f2bs(fmaxf(acc, 0.0f));
    }
}

// ---- Layer 2 aggregate: agg2[n][:] = sum h1[esrc][:] -----------------------
__global__ void gather2_kernel(const unsigned* __restrict__ h1,
                               const int* __restrict__ ptr,
                               const int* __restrict__ esrc,
                               unsigned* __restrict__ agg2) {
    int lane = threadIdx.x & 63;
    int sub  = lane & 31;
    int half = lane >> 5;
    int w    = (blockIdx.x * blockDim.x + threadIdx.x) >> 6;
    int nw   = (gridDim.x * blockDim.x) >> 6;
    for (int n = w; n < N_NODES; n += nw) {
        int start = rfl(ptr[n]);
        int end   = rfl((n + 1 < N_NODES) ? ptr[n + 1] : N_EDGES);
        float ax0 = 0.f, ay0 = 0.f, ax1 = 0.f, ay1 = 0.f;
        int e = start + half;
        for (; e + 2 < end; e += 4) {              // two edges per half-wave iter
            int s0 = esrc[e], s1 = esrc[e + 2];
            unsigned p0 = h1[(size_t)s0 * 32 + sub];
            unsigned p1 = h1[(size_t)s1 * 32 + sub];
            ax0 += bs2f((unsigned short)(p0 & 0xffff));
            ay0 += bs2f((unsigned short)(p0 >> 16));
            ax1 += bs2f((unsigned short)(p1 & 0xffff));
            ay1 += bs2f((unsigned short)(p1 >> 16));
        }
        if (e < end) {
            unsigned p = h1[(size_t)esrc[e] * 32 + sub];
            ax0 += bs2f((unsigned short)(p & 0xffff));
            ay0 += bs2f((unsigned short)(p >> 16));
        }
        float ax = ax0 + ax1, ay = ay0 + ay1;
        ax += __shfl_xor(ax, 32, 64);
        ay += __shfl_xor(ay, 32, 64);
        if (half == 0) {
            unsigned outw = ((unsigned)f2bs(ay) << 16) | (unsigned)f2bs(ax);
            agg2[(size_t)n * 32 + sub] = outw;
        }
    }
}

// ---- Layer 2 transform via MFMA: h2 = relu([agg2|h1] @ [Wr;Wo] + b) --------
__global__ void mlp2_mfma(const unsigned short* __restrict__ agg2,
                          const unsigned short* __restrict__ h1,
                          const float* __restrict__ w_rel2,
                          const float* __restrict__ b_rel2,
                          const float* __restrict__ w_root2,
                          unsigned short* __restrict__ h2) {
    int lane = threadIdx.x & 63;
    int wv   = threadIdx.x >> 6;        // 0..3 column group
    int row  = lane & 15;
    int quad = lane >> 4;
    int n    = wv * 16 + row;           // this lane's output column

    short8 bwr[2], bwo[2];
#pragma unroll
    for (int s = 0; s < 2; ++s)
#pragma unroll
        for (int j = 0; j < 8; ++j) {
            int k = 32 * s + quad * 8 + j;
            bwr[s][j] = (short)f2bs(w_rel2[k * HIDDEN + n]);
            bwo[s][j] = (short)f2bs(w_root2[k * HIDDEN + n]);
        }
    float bias = b_rel2[n];

    for (int t = blockIdx.x; t < M_TILES; t += gridDim.x) {
        int m0 = t * 16;
        size_t rbase = (size_t)(m0 + row) * HIDDEN;
        short8 aa0 = *(const short8*)(agg2 + rbase + quad * 8);
        short8 aa1 = *(const short8*)(agg2 + rbase + 32 + quad * 8);
        short8 ah0 = *(const short8*)(h1   + rbase + quad * 8);
        short8 ah1 = *(const short8*)(h1   + rbase + 32 + quad * 8);

        f32x4 acc = {bias, bias, bias, bias};
        acc = __builtin_amdgcn_mfma_f32_16x16x32_bf16(aa0, bwr[0], acc, 0, 0, 0);
        acc = __builtin_amdgcn_mfma_f32_16x16x32_bf16(aa1, bwr[1], acc, 0, 0, 0);
        acc = __builtin_amdgcn_mfma_f32_16x16x32_bf16(ah0, bwo[0], acc, 0, 0, 0);
        acc = __builtin_amdgcn_mfma_f32_16x16x32_bf16(ah1, bwo[1], acc, 0, 0, 0);

#pragma unroll
        for (int i = 0; i < 4; ++i) {
            int m = m0 + quad * 4 + i;
            h2[(size_t)m * HIDDEN + n] = f2bs(fmaxf(acc[i], 0.0f));
        }
    }
}

// ---- Pool stage 1: segmented add over sorted batch -> add_pool[G][64] ------
// 1024 waves; each wave owns a contiguous ~98-node slice, accumulates per-dim
// partials in registers, flushes one atomicAdd per graph-segment per dim.
__global__ void pool_partial(const unsigned short* __restrict__ h2,
                             const int* __restrict__ batch,
                             float* __restrict__ add_pool) {
    int lane   = threadIdx.x & 63;
    int waveId = (blockIdx.x * blockDim.x + threadIdx.x) >> 6;
    int nWaves = (gridDim.x * blockDim.x) >> 6;
    int per = (N_NODES + nWaves - 1) / nWaves;
    int n0 = waveId * per;
    int n1 = n0 + per; if (n1 > N_NODES) n1 = N_NODES;
    if (n0 >= n1) return;

    float acc = 0.0f;
    int curg = rfl(batch[n0]);
    for (int n = n0; n < n1; ++n) {
        int g = rfl(batch[n]);
        if (g != curg) {
            atomicAdd(&add_pool[curg * HIDDEN + lane], acc);
            acc = 0.0f;
            curg = g;
        }
        acc += bs2f(h2[(size_t)n * HIDDEN + lane]);
    }
    atomicAdd(&add_pool[curg * HIDDEN + lane], acc);
}

// ---- Pool stage 2 + MLP head: one block (64 threads) per graph -------------
__device__ __forceinline__ int lower_bound_i(const int* a, int n, int v) {
    int lo = 0, hi = n;
    while (lo < hi) { int mid = (lo + hi) >> 1; if (a[mid] < v) lo = mid + 1; else hi = mid; }
    return lo;
}

__global__ void head_mlp(const float* __restrict__ add_pool,
                         const int* __restrict__ batch,
                         const float* __restrict__ w_h1,
                         const float* __restrict__ b_h1,
                         const float* __restrict__ w_h2,
                         const float* __restrict__ b_h2,
                         float* __restrict__ out) {
    int g = blockIdx.x, t = threadIdx.x;

    __shared__ int s_cnt;
    if (t == 0) {
        int start = lower_bound_i(batch, N_NODES, g);
        int end   = lower_bound_i(batch, N_NODES, g + 1);
        s_cnt = end - start;
    }
    __syncthreads();
    float cnt = fmaxf((float)s_cnt, 1.0f);

    __shared__ float sg[2 * HIDDEN];
    float add = add_pool[(size_t)g * HIDDEN + t];
    sg[t]          = add / cnt;   // mean_pool
    sg[HIDDEN + t] = add;         // add_pool
    __syncthreads();

    float hid = b_h1[t];
#pragma unroll 16
    for (int i = 0; i < 2 * HIDDEN; ++i)
        hid += sg[i] * w_h1[i * HIDDEN + t];
    hid = fmaxf(hid, 0.0f);

    float res = hid * w_h2[t];
    for (int off = 32; off > 0; off >>= 1)
        res += __shfl_down(res, off, 64);
    if (t == 0) out[g] = res + b_h2[0];
}

extern "C" void kernel_launch(void* const* d_in, const int* in_sizes, int n_in,
                              void* d_out, int out_size, void* d_ws, size_t ws_size,
                              hipStream_t stream) {
    const float* x       = (const float*)d_in[0];
    const int*   ei      = (const int*)d_in[1];
    const int*   src     = ei;
    const int*   dst     = ei + N_EDGES;
    const int*   batch   = (const int*)d_in[2];
    const float* w_rel1  = (const float*)d_in[3];
    const float* b_rel1  = (const float*)d_in[4];
    const float* w_root1 = (const float*)d_in[5];
    const float* w_rel2  = (const float*)d_in[6];
    const float* b_rel2  = (const float*)d_in[7];
    const float* w_root2 = (const float*)d_in[8];
    const float* w_h1    = (const float*)d_in[9];
    const float* b_h1    = (const float*)d_in[10];
    const float* w_h2    = (const float*)d_in[11];
    const float* b_h2    = (const float*)d_in[12];
    float* out = (float*)d_out;

    // workspace layout:
    // [ptr: N | add_pool: 128*64 f32 | blockSums: 128 | rank: E | esrc: E |
    //  h1: N*64 bf16 | agg2 | h2]   (ptr+add_pool zeroed in one memset)
    int*            ptr       = (int*)d_ws;
    float*          add_pool  = (float*)(ptr + ((N_NODES + 31) & ~31));
    int*            blockSums = (int*)(add_pool + NUM_GRAPHS * HIDDEN);
    int*            rank      = blockSums + 128;
    int*            esrc      = rank + N_EDGES;
    unsigned short* h1        = (unsigned short*)(esrc + N_EDGES);
    unsigned short* agg2      = h1 + (size_t)N_NODES * HIDDEN;
    unsigned short* h2        = agg2 + (size_t)N_NODES * HIDDEN;

    size_t zero_bytes = (char*)(add_pool + NUM_GRAPHS * HIDDEN) - (char*)d_ws;
    hipMemsetAsync(d_ws, 0, zero_bytes, stream);

    hist_rank<<<(N_EDGES / 4 + 255) / 256, 256, 0, stream>>>(dst, ptr, rank);
    scan1_kernel<<<SCAN_NB, SCAN_BLOCK, 0, stream>>>(ptr, blockSums);
    scan2_kernel<<<1, 128, 0, stream>>>(blockSums);
    scan3_kernel<<<(N_NODES + 255) / 256, 256, 0, stream>>>(ptr, blockSums);
    scatter_fill<<<(N_EDGES / 4 + 255) / 256, 256, 0, stream>>>(src, dst, rank, ptr, esrc);

    gather_mlp1<<<1024, 256, 0, stream>>>(x, ptr, esrc, w_rel1, b_rel1, w_root1, h1);
    gather2_kernel<<<2048, 256, 0, stream>>>((const unsigned*)h1, ptr, esrc, (unsigned*)agg2);
    mlp2_mfma<<<2048, 256, 0, stream>>>(agg2, h1, w_rel2, b_rel2, w_root2, h2);
    pool_partial<<<POOL_BLOCKS, 256, 0, stream>>>(h2, batch, add_pool);
    head_mlp<<<NUM_GRAPHS, 64, 0, stream>>>(add_pool, batch, w_h1, b_h1, w_h2, b_h2, out);
}